// Round 6
// baseline (2116.778 us; speedup 1.0000x reference)
//
#include <hip/hip_runtime.h>
#include <hip/hip_bf16.h>

#define Vv 32000
#define Tz 256
#define Hz 256

typedef __attribute__((ext_vector_type(8))) short short8;
typedef __attribute__((ext_vector_type(4))) float f32x4;

__device__ __forceinline__ float sigm(float x) { return 1.f / (1.f + __expf(-x)); }
__device__ __forceinline__ float tanh_(float x) {
    float e = __expf(2.f * x);
    return 1.f - 2.f / (e + 1.f);
}
__device__ __forceinline__ unsigned short f2bf(float x) {
    union { __hip_bfloat16 h; unsigned short u; } cv; cv.h = __float2bfloat16(x); return cv.u;
}
__device__ __forceinline__ float bf2f(unsigned short u) {
    union { unsigned u; float f; } cv; cv.u = ((unsigned)u) << 16; return cv.f;
}
__device__ __forceinline__ void waitge(unsigned* f, unsigned tgt) {
    while (__hip_atomic_load(f, __ATOMIC_ACQUIRE, __HIP_MEMORY_SCOPE_AGENT) < tgt)
        __builtin_amdgcn_s_sleep(1);
}

// ---------- embedding gather -> xs_bf [T][B][256] bf16 (row = t*32+b)
__global__ __launch_bounds__(64) void k_embed(const int* __restrict__ inp,
    const float* __restrict__ emb, __hip_bfloat16* __restrict__ xs) {
    int row = blockIdx.x;
    int t = row >> 5, b = row & 31;
    const float* src = emb + (size_t)inp[b * Tz + t] * Hz;
    int tid = threadIdx.x;
    float4 v = *(const float4*)&src[tid * 4];
    __hip_bfloat16* dst = xs + (size_t)row * Hz + tid * 4;
    dst[0] = __float2bfloat16(v.x); dst[1] = __float2bfloat16(v.y);
    dst[2] = __float2bfloat16(v.z); dst[3] = __float2bfloat16(v.w);
}

// ---------- W [512 k][1024 zc] f32 -> gate-grouped bf16: G[o][gi][k'] with
// gi = hid_local*4 + gate, zc = gate*256 + o*128 + hid_local, k' = k mod 256.
// Four outputs per layer-half: {W1xG, W1hG} from W1, {W2xG, W2hG} from W2.
__global__ __launch_bounds__(256) void k_wt(const float* __restrict__ W1,
    const float* __restrict__ W2, unsigned short* __restrict__ W1xG,
    unsigned short* __restrict__ W1hG, unsigned short* __restrict__ W2xG,
    unsigned short* __restrict__ W2hG) {
    __shared__ float tile[64][65];
    int bid = blockIdx.x;              // 256 blocks: layer x 8 ktiles x 16 zctiles
    int layer = bid >> 7;
    int tl = bid & 127;
    int kt = tl & 7, zt = tl >> 3;
    int k0 = kt * 64, zc0 = zt * 64;
    const float* W = layer ? W2 : W1;
    unsigned short* dst;
    if (!layer) dst = (k0 < 256) ? W1xG : W1hG;
    else        dst = (k0 < 256) ? W2xG : W2hG;
    int o = (zc0 >> 7) & 1, g = zc0 >> 8, hid0 = zc0 & 127;
    int kb = k0 & 255;
    int tid = threadIdx.x;
#pragma unroll
    for (int p = 0; p < 16; ++p) {
        int lin = p * 256 + tid;
        int kk = lin >> 6, zz = lin & 63;
        tile[kk][zz] = W[(size_t)(k0 + kk) * 1024 + zc0 + zz];
    }
    __syncthreads();
#pragma unroll
    for (int p = 0; p < 16; ++p) {
        int lin = p * 256 + tid;
        int zz = lin >> 6, kk = lin & 63;
        dst[((size_t)o * 512 + (hid0 + zz) * 4 + g) * 256 + kb + kk] = f2bf(tile[kk][zz]);
    }
}

// ---------- z1x precompute: [8192][256] @ W1xG^T -> z1xG [8192][1024] bf16 (cols grouped (o,gi))
__global__ __launch_bounds__(256) void k_xw(const __hip_bfloat16* __restrict__ Abf,
    const unsigned short* __restrict__ Bg, unsigned short* __restrict__ outG)
{
    __shared__ __align__(16) unsigned short As[128 * 64];
    __shared__ __align__(16) unsigned short Bs[128 * 64];
    int tid = threadIdx.x;
    size_t r0 = (size_t)blockIdx.x * 128;
    size_t c0 = (size_t)blockIdx.y * 128;
    int l = tid & 63, w = tid >> 6, lr = l & 15, lk = l >> 4;
    f32x4 acc[2][8];
#pragma unroll
    for (int m = 0; m < 2; ++m)
#pragma unroll
        for (int f = 0; f < 8; ++f) acc[m][f] = (f32x4){0.f, 0.f, 0.f, 0.f};
    const unsigned short* A = (const unsigned short*)Abf;
    for (int kt = 0; kt < 4; ++kt) {
#pragma unroll
        for (int i = 0; i < 4; ++i) {
            int fi = i * 256 + tid;
            int row = fi >> 3, seg = fi & 7;
            int dseg = seg ^ (row & 7);
            *(short8*)&As[row * 64 + dseg * 8] =
                *(const short8*)&A[(r0 + row) * 256 + kt * 64 + seg * 8];
            *(short8*)&Bs[row * 64 + dseg * 8] =
                *(const short8*)&Bg[((size_t)c0 + row) * 256 + kt * 64 + seg * 8];
        }
        __syncthreads();
#pragma unroll
        for (int ks = 0; ks < 2; ++ks) {
            short8 a[2];
#pragma unroll
            for (int m = 0; m < 2; ++m) {
                int row = w * 32 + m * 16 + lr;
                a[m] = *(const short8*)&As[row * 64 + ((ks * 4 + lk) ^ (row & 7)) * 8];
            }
#pragma unroll
            for (int f = 0; f < 8; ++f) {
                int row = f * 16 + lr;
                short8 bfr = *(const short8*)&Bs[row * 64 + ((ks * 4 + lk) ^ (row & 7)) * 8];
#pragma unroll
                for (int m = 0; m < 2; ++m)
                    acc[m][f] = __builtin_amdgcn_mfma_f32_16x16x32_bf16(a[m], bfr, acc[m][f], 0, 0, 0);
            }
        }
        __syncthreads();
    }
#pragma unroll
    for (int f = 0; f < 8; ++f)
#pragma unroll
        for (int m = 0; m < 2; ++m)
#pragma unroll
            for (int j = 0; j < 4; ++j)
                outG[(r0 + w * 32 + m * 16 + lk * 4 + j) * 1024 + c0 + f * 16 + lr] =
                    f2bf(acc[m][f][j]);
}

// ---------- persistent LSTM pipeline: A{0,8} h1-recur, B{1,9} z2x, C{2,10} h2-recur,
// 10 spare blocks do the softmax_w transpose. Pairwise/forward-only flags only.
#define HSTR 264          // LDS h row stride (bf16): 528 B = 33 slots (odd) -> low conflict
#define RING 16
__global__ __launch_bounds__(512, 2) void k_lstm4(
    const unsigned short* __restrict__ z1xG,     // [8192][1024] bf16
    const unsigned short* __restrict__ W1hG,     // [2][512][256] bf16
    const unsigned short* __restrict__ W2xG,
    const unsigned short* __restrict__ W2hG,
    const float* __restrict__ b1v, const float* __restrict__ b2v,
    unsigned short* __restrict__ h1hist,         // [256][32][256]
    unsigned short* __restrict__ z2xR,           // [RING][2][32][512]
    unsigned short* __restrict__ houtB,          // [8192][256] (row = b*256+t)
    unsigned* __restrict__ flags,
    const float* __restrict__ sw, __hip_bfloat16* __restrict__ swt)
{
    __shared__ __align__(16) unsigned short hbuf[32 * HSTR];
    __shared__ float tile[64][65];

    int bid = blockIdx.x;
    int tid = threadIdx.x;
    int stage = -1, o = 0;
    if      (bid == 0)  { stage = 0; o = 0; }
    else if (bid == 8)  { stage = 0; o = 1; }
    else if (bid == 1)  { stage = 1; o = 0; }
    else if (bid == 9)  { stage = 1; o = 1; }
    else if (bid == 2)  { stage = 2; o = 0; }
    else if (bid == 10) { stage = 2; o = 1; }

    if (stage < 0) {
        // folded softmax_w transpose: [256][32000] f32 -> [32000][256] bf16
        int idx = (bid < 8) ? (bid - 3) : (bid - 11 + 5);   // 0..9
        for (int tl = idx; tl < 2000; tl += 10) {
            int kt = tl & 3, vt = tl >> 2;
            int k0 = kt * 64, v0 = vt * 64;
#pragma unroll
            for (int pp = 0; pp < 8; ++pp) {
                int lin = pp * 512 + tid;
                int kk = lin >> 6, vv = lin & 63;
                tile[kk][vv] = sw[(size_t)(k0 + kk) * Vv + v0 + vv];
            }
            __syncthreads();
#pragma unroll
            for (int pp = 0; pp < 8; ++pp) {
                int lin = pp * 512 + tid;
                int vv = lin >> 6, kk = lin & 63;
                swt[(size_t)(v0 + vv) * 256 + k0 + kk] = __float2bfloat16(tile[kk][vv]);
            }
            __syncthreads();
        }
        return;
    }

    int w = tid >> 6, l = tid & 63, lr = l & 15, lk = l >> 4;
    int po = 1 - o;

    unsigned* fA0 = flags +  0; unsigned* fA1 = flags + 16;
    unsigned* fB0 = flags + 32; unsigned* fB1 = flags + 48;
    unsigned* fC0 = flags + 64; unsigned* fC1 = flags + 80;
    unsigned* myf   = (stage == 0) ? (o ? fA1 : fA0)
                    : (stage == 1) ? (o ? fB1 : fB0) : (o ? fC1 : fC0);
    unsigned* partf = (stage == 0) ? (o ? fA0 : fA1)
                    : (stage == 2) ? (o ? fC0 : fC1) : (unsigned*)0;
    unsigned* srcf  = (stage == 2) ? (o ? fB1 : fB0) : (unsigned*)0;
    unsigned* consf = (stage == 1) ? (o ? fC1 : fC0) : (unsigned*)0;

    // ---- weight fragments -> VGPRs (gate-grouped): 32 short8 = 128 VGPR/lane
    const unsigned short* WG =
        ((stage == 0) ? W1hG : (stage == 1) ? W2xG : W2hG) + (size_t)o * 512 * 256;
    short8 Wf[4][8];
#pragma unroll
    for (int hbl = 0; hbl < 4; ++hbl)
#pragma unroll
        for (int kc = 0; kc < 8; ++kc)
            Wf[hbl][kc] = *(const short8*)&WG[((w * 4 + hbl) * 16 + lr) * 256 + kc * 32 + lk * 8];

    float4 bq[4];
    float c_[4][2];
    if (stage != 1) {
        const float* bv = (stage == 0) ? b1v : b2v;
#pragma unroll
        for (int hbl = 0; hbl < 4; ++hbl) {
            int hidl = (w * 4 + hbl) * 4 + lk;
            bq[hbl].x = bv[0 * 256 + o * 128 + hidl];
            bq[hbl].y = bv[1 * 256 + o * 128 + hidl];
            bq[hbl].z = bv[2 * 256 + o * 128 + hidl];
            bq[hbl].w = bv[3 * 256 + o * 128 + hidl];
#pragma unroll
            for (int bh = 0; bh < 2; ++bh) c_[hbl][bh] = 0.f;
        }
        for (int u = tid; u < 32 * HSTR; u += 512) hbuf[u] = 0;   // h(-1) = 0
    }

    int cb = tid >> 4, cseg = tid & 15;     // copy thread mapping

    for (int t = 0; t < 256; ++t) {
        if (stage == 1) {
            // ================= stage B: z2x(t) = h1(t) @ Wx2 =================
            if (tid == 0) {
                waitge(fA0, t + 1); waitge(fA1, t + 1);
                if (t >= RING - 1) waitge(consf, (unsigned)(t - (RING - 2)));
            }
            __syncthreads();
            {
                short8 v0 = *(const short8*)&h1hist[((size_t)t * 32 + cb) * 256 + cseg * 8];
                short8 v1 = *(const short8*)&h1hist[((size_t)t * 32 + cb) * 256 + 128 + cseg * 8];
                *(short8*)&hbuf[cb * HSTR + cseg * 8] = v0;
                *(short8*)&hbuf[cb * HSTR + 128 + cseg * 8] = v1;
            }
            __syncthreads();
            f32x4 acc[4][2];
#pragma unroll
            for (int hbl = 0; hbl < 4; ++hbl)
#pragma unroll
                for (int bh = 0; bh < 2; ++bh) acc[hbl][bh] = (f32x4){0.f, 0.f, 0.f, 0.f};
#pragma unroll
            for (int kc = 0; kc < 8; ++kc) {
                short8 h0 = *(const short8*)&hbuf[lr * HSTR + kc * 32 + lk * 8];
                short8 h1 = *(const short8*)&hbuf[(16 + lr) * HSTR + kc * 32 + lk * 8];
#pragma unroll
                for (int hbl = 0; hbl < 4; ++hbl) {
                    acc[hbl][0] = __builtin_amdgcn_mfma_f32_16x16x32_bf16(Wf[hbl][kc], h0, acc[hbl][0], 0, 0, 0);
                    acc[hbl][1] = __builtin_amdgcn_mfma_f32_16x16x32_bf16(Wf[hbl][kc], h1, acc[hbl][1], 0, 0, 0);
                }
            }
            unsigned short* zdst = z2xR + (((size_t)(t & (RING - 1)) * 2 + o) * 32) * 512;
#pragma unroll
            for (int hbl = 0; hbl < 4; ++hbl) {
                int hidl = (w * 4 + hbl) * 4 + lk;
#pragma unroll
                for (int bh = 0; bh < 2; ++bh) {
                    unsigned lo = (unsigned)f2bf(acc[hbl][bh][0]) | ((unsigned)f2bf(acc[hbl][bh][1]) << 16);
                    unsigned hi = (unsigned)f2bf(acc[hbl][bh][2]) | ((unsigned)f2bf(acc[hbl][bh][3]) << 16);
                    *(uint2*)&zdst[(bh * 16 + lr) * 512 + hidl * 4] = make_uint2(lo, hi);
                }
            }
            __syncthreads();   // drains vmcnt before flag
            if (tid == 0)
                __hip_atomic_store(myf, (unsigned)(t + 1), __ATOMIC_RELEASE, __HIP_MEMORY_SCOPE_AGENT);
        } else {
            // ================= stage A / C: recurrence =================
            if (stage == 2 && tid == 0) waitge(srcf, (unsigned)(t + 1));
            __syncthreads();   // barA: partner h(t-1) (and B-flag broadcast) visible

            // addend prefetch (4 bf16 gate-quads per (hbl,bh))
            uint2 ad[4][2];
            if (stage == 0) {
#pragma unroll
                for (int hbl = 0; hbl < 4; ++hbl) {
                    int hidl = (w * 4 + hbl) * 4 + lk;
#pragma unroll
                    for (int bh = 0; bh < 2; ++bh)
                        ad[hbl][bh] = *(const uint2*)&z1xG[((size_t)t * 32 + bh * 16 + lr) * 1024 + o * 512 + hidl * 4];
                }
            } else {
                const unsigned short* zsrc = z2xR + (((size_t)(t & (RING - 1)) * 2 + o) * 32) * 512;
#pragma unroll
                for (int hbl = 0; hbl < 4; ++hbl) {
                    int hidl = (w * 4 + hbl) * 4 + lk;
#pragma unroll
                    for (int bh = 0; bh < 2; ++bh)
                        ad[hbl][bh] = *(const uint2*)&zsrc[(bh * 16 + lr) * 512 + hidl * 4];
                }
            }

            f32x4 acc[4][2];
#pragma unroll
            for (int hbl = 0; hbl < 4; ++hbl)
#pragma unroll
                for (int bh = 0; bh < 2; ++bh) acc[hbl][bh] = (f32x4){0.f, 0.f, 0.f, 0.f};
#pragma unroll
            for (int kc = 0; kc < 8; ++kc) {
                short8 h0 = *(const short8*)&hbuf[lr * HSTR + kc * 32 + lk * 8];
                short8 h1 = *(const short8*)&hbuf[(16 + lr) * HSTR + kc * 32 + lk * 8];
#pragma unroll
                for (int hbl = 0; hbl < 4; ++hbl) {
                    acc[hbl][0] = __builtin_amdgcn_mfma_f32_16x16x32_bf16(Wf[hbl][kc], h0, acc[hbl][0], 0, 0, 0);
                    acc[hbl][1] = __builtin_amdgcn_mfma_f32_16x16x32_bf16(Wf[hbl][kc], h1, acc[hbl][1], 0, 0, 0);
                }
            }

            // gates fully in-register (reg j = gate: i,j,f,o)
            unsigned short hu[4][2];
#pragma unroll
            for (int hbl = 0; hbl < 4; ++hbl)
#pragma unroll
                for (int bh = 0; bh < 2; ++bh) {
                    float zi = acc[hbl][bh][0] + bf2f((unsigned short)(ad[hbl][bh].x & 0xffff)) + bq[hbl].x;
                    float zj = acc[hbl][bh][1] + bf2f((unsigned short)(ad[hbl][bh].x >> 16)) + bq[hbl].y;
                    float zf = acc[hbl][bh][2] + bf2f((unsigned short)(ad[hbl][bh].y & 0xffff)) + bq[hbl].z;
                    float zo = acc[hbl][bh][3] + bf2f((unsigned short)(ad[hbl][bh].y >> 16)) + bq[hbl].w;
                    float cn = c_[hbl][bh] * sigm(zf + 1.f) + sigm(zi) * tanh_(zj);
                    c_[hbl][bh] = cn;
                    hu[hbl][bh] = f2bf(tanh_(cn) * sigm(zo));
                }

            __syncthreads();   // barB: all MFMA reads of h(t-1) complete
#pragma unroll
            for (int hbl = 0; hbl < 4; ++hbl) {
                int hidl = (w * 4 + hbl) * 4 + lk;
#pragma unroll
                for (int bh = 0; bh < 2; ++bh)
                    hbuf[(bh * 16 + lr) * HSTR + o * 128 + hidl] = hu[hbl][bh];
            }
            __syncthreads();   // barC: h(t) own half visible in LDS

            // publish own half (coalesced from LDS)
            {
                short8 v = *(const short8*)&hbuf[cb * HSTR + o * 128 + cseg * 8];
                if (stage == 0)
                    *(short8*)&h1hist[((size_t)t * 32 + cb) * 256 + o * 128 + cseg * 8] = v;
                else
                    *(short8*)&houtB[((size_t)cb * 256 + t) * 256 + o * 128 + cseg * 8] = v;
            }
            __syncthreads();   // barD: vmcnt drained before flag
            if (tid == 0) {
                __hip_atomic_store(myf, (unsigned)(t + 1), __ATOMIC_RELEASE, __HIP_MEMORY_SCOPE_AGENT);
                if (t < 255) waitge(partf, (unsigned)(t + 1));
            }
            __syncthreads();   // barE
            if (t < 255) {     // fetch partner half of h(t)
                short8 v;
                if (stage == 0)
                    v = *(const short8*)&h1hist[((size_t)t * 32 + cb) * 256 + po * 128 + cseg * 8];
                else
                    v = *(const short8*)&houtB[((size_t)cb * 256 + t) * 256 + po * 128 + cseg * 8];
                *(short8*)&hbuf[cb * HSTR + po * 128 + cseg * 8] = v;
            }
        }
    }
}

// ---------- logits GEMM: 128x128 tile, BK=64, XOR-swizzled LDS, streaming sum-of-exp
__global__ __launch_bounds__(256) void k_gemm(const __hip_bfloat16* __restrict__ Abf,
    const __hip_bfloat16* __restrict__ Bbf, const float* __restrict__ sb,
    float* __restrict__ row_sum)
{
    __shared__ __align__(16) unsigned short As[128 * 64];
    __shared__ __align__(16) unsigned short Bs[128 * 64];
    int tid = threadIdx.x;
    size_t r0 = (size_t)blockIdx.x * 128;
    size_t c0 = (size_t)blockIdx.y * 128;
    int l = tid & 63, w = tid >> 6, lr = l & 15, lk = l >> 4;

    f32x4 acc[2][8];
#pragma unroll
    for (int m = 0; m < 2; ++m)
#pragma unroll
        for (int f = 0; f < 8; ++f) acc[m][f] = (f32x4){0.f, 0.f, 0.f, 0.f};

    const unsigned short* A = (const unsigned short*)Abf;
    const unsigned short* B = (const unsigned short*)Bbf;

    for (int kt = 0; kt < 4; ++kt) {
#pragma unroll
        for (int i = 0; i < 4; ++i) {
            int fi = i * 256 + tid;
            int row = fi >> 3, seg = fi & 7;
            int dseg = seg ^ (row & 7);
            *(short8*)&As[row * 64 + dseg * 8] =
                *(const short8*)&A[(r0 + row) * 256 + kt * 64 + seg * 8];
            *(short8*)&Bs[row * 64 + dseg * 8] =
                *(const short8*)&B[(c0 + row) * 256 + kt * 64 + seg * 8];
        }
        __syncthreads();
#pragma unroll
        for (int ks = 0; ks < 2; ++ks) {
            short8 a[2];
#pragma unroll
            for (int m = 0; m < 2; ++m) {
                int row = w * 32 + m * 16 + lr;
                a[m] = *(const short8*)&As[row * 64 + ((ks * 4 + lk) ^ (row & 7)) * 8];
            }
#pragma unroll
            for (int f = 0; f < 8; ++f) {
                int row = f * 16 + lr;
                short8 bfr = *(const short8*)&Bs[row * 64 + ((ks * 4 + lk) ^ (row & 7)) * 8];
#pragma unroll
                for (int m = 0; m < 2; ++m)
                    acc[m][f] = __builtin_amdgcn_mfma_f32_16x16x32_bf16(a[m], bfr, acc[m][f], 0, 0, 0);
            }
        }
        __syncthreads();
    }

    float sums[2][4] = {{0.f,0.f,0.f,0.f},{0.f,0.f,0.f,0.f}};
#pragma unroll
    for (int f = 0; f < 8; ++f) {
        float sbv = sb[c0 + f * 16 + lr];
#pragma unroll
        for (int m = 0; m < 2; ++m)
#pragma unroll
            for (int j = 0; j < 4; ++j) sums[m][j] += __expf(acc[m][f][j] + sbv);
    }
#pragma unroll
    for (int msk = 1; msk <= 8; msk <<= 1)
#pragma unroll
        for (int m = 0; m < 2; ++m)
#pragma unroll
            for (int j = 0; j < 4; ++j) sums[m][j] += __shfl_xor(sums[m][j], msk);
    if (lr == 0) {
#pragma unroll
        for (int m = 0; m < 2; ++m)
#pragma unroll
            for (int j = 0; j < 4; ++j)
                atomicAdd(&row_sum[r0 + w * 32 + m * 16 + lk * 4 + j], sums[m][j]);
    }
}

// ---------- per-row loss: log(sum_exp) - target logit
__global__ __launch_bounds__(256) void k_loss(const __hip_bfloat16* __restrict__ houtB,
    const __hip_bfloat16* __restrict__ swt, const float* __restrict__ sb,
    const int* __restrict__ tgts, const float* __restrict__ row_sum,
    float* __restrict__ out)
{
    int r = blockIdx.x * 256 + threadIdx.x;
    int tg = tgts[r];
    const unsigned short* h = (const unsigned short*)houtB + (size_t)r * Hz;
    const unsigned short* wp = (const unsigned short*)swt + (size_t)tg * Hz;
    float acc = 0.f;
#pragma unroll 4
    for (int k8 = 0; k8 < 32; ++k8) {
        short8 hv = *(const short8*)&h[k8 * 8];
        short8 wv = *(const short8*)&wp[k8 * 8];
#pragma unroll
        for (int e = 0; e < 8; ++e)
            acc += bf2f((unsigned short)hv[e]) * bf2f((unsigned short)wv[e]);
    }
    float loss = logf(row_sum[r]) - (acc + sb[tg]);
#pragma unroll
    for (int m = 1; m < 64; m <<= 1) loss += __shfl_xor(loss, m);
    __shared__ float red[4];
    int l = threadIdx.x & 63, wvv = threadIdx.x >> 6;
    if (l == 0) red[wvv] = loss;
    __syncthreads();
    if (threadIdx.x == 0) {
        float s = red[0] + red[1] + red[2] + red[3];
        atomicAdd(out, s * (1.f / 8192.f));
    }
}

extern "C" void kernel_launch(void* const* d_in, const int* in_sizes, int n_in,
                              void* d_out, int out_size, void* d_ws, size_t ws_size,
                              hipStream_t stream)
{
    const int*   inp = (const int*)d_in[0];
    const int*   tgt = (const int*)d_in[1];
    const float* emb = (const float*)d_in[2];
    const float* W1  = (const float*)d_in[3];
    const float* b1  = (const float*)d_in[4];
    const float* W2  = (const float*)d_in[5];
    const float* b2  = (const float*)d_in[6];
    const float* sw  = (const float*)d_in[7];
    const float* sb  = (const float*)d_in[8];
    float* out = (float*)d_out;

    char* ws = (char*)d_ws;
    size_t off = 0;
    __hip_bfloat16* SWT  = (__hip_bfloat16*)(ws + off); off += (size_t)Vv * Hz * 2;       // 16,384,000
    __hip_bfloat16* XS   = (__hip_bfloat16*)(ws + off); off += (size_t)Tz * 32 * Hz * 2;  //  4,194,304
    unsigned short* W1xG = (unsigned short*)(ws + off); off += (size_t)1024 * 256 * 2;    //    524,288
    unsigned short* W1hG = (unsigned short*)(ws + off); off += (size_t)1024 * 256 * 2;
    unsigned short* W2xG = (unsigned short*)(ws + off); off += (size_t)1024 * 256 * 2;
    unsigned short* W2hG = (unsigned short*)(ws + off); off += (size_t)1024 * 256 * 2;
    unsigned short* Z1xG = (unsigned short*)(ws + off); off += (size_t)8192 * 1024 * 2;   // 16,777,216
    unsigned short* Z2xR = (unsigned short*)(ws + off); off += (size_t)RING * 2 * 32 * 512 * 2; // 1,048,576
    unsigned short* H1h  = (unsigned short*)(ws + off); off += (size_t)Tz * 32 * 256 * 2; //  4,194,304
    unsigned short* HoutB= (unsigned short*)(ws + off); off += (size_t)8192 * Hz * 2;     //  4,194,304
    float* row_sum       = (float*)(ws + off);          off += 8192 * 4;                  //     32,768
    unsigned* flags      = (unsigned*)(ws + off);       off += 96 * 4;                    //        384
    // total ~49 MiB

    hipMemsetAsync(row_sum, 0, 8192 * 4 + 96 * 4, stream);   // row_sum + flags
    hipMemsetAsync(out, 0, sizeof(float), stream);

    k_embed<<<8192, 64, 0, stream>>>(inp, emb, XS);
    k_wt<<<256, 256, 0, stream>>>(W1, W2, W1xG, W1hG, W2xG, W2hG);
    k_xw<<<dim3(64, 8), 256, 0, stream>>>(XS, W1xG, Z1xG);
    k_lstm4<<<16, 512, 0, stream>>>(Z1xG, W1hG, W2xG, W2hG, b1, b2,
                                    H1h, Z2xR, HoutB, flags, sw, SWT);
    k_gemm<<<dim3(64, 250), 256, 0, stream>>>((const __hip_bfloat16*)HoutB, SWT, sb, row_sum);
    k_loss<<<32, 256, 0, stream>>>((const __hip_bfloat16*)HoutB, SWT, sb, tgt, row_sum, out);
}